// Round 5
// baseline (56.323 us; speedup 1.0000x reference)
//
#include <hip/hip_runtime.h>
#include <hip/hip_bf16.h>
#include <math.h>

#define KBINS 5
#define NF 4
#define BV 3.0f

typedef float f32x4 __attribute__((ext_vector_type(4)));
typedef float f32x2 __attribute__((ext_vector_type(2)));

// LDS tbl layout (floats):
//   [0,160):  f*40 + k*8 + {cw, iw, ch, h, dl, dr, -, -}
//   [160,176): interior boundaries: f*4 + j = cumw[j+1]
//   [176,179): mu, c0, ivar
#define BND_OFF 160

__global__ __launch_bounds__(256, 4) void nsf_all(
    const float* __restrict__ xin,
    const float* __restrict__ layers,
    const float* __restrict__ ip,
    float* __restrict__ out,
    long n) {
    __shared__ __align__(16) float tbl[180];
    const int t = threadIdx.x;
    // ---- in-block prep: 13 writer threads, disjoint slots ----
    if (t < 12) {
        const int f = t & 3;
        const int role = t >> 2;
        const float* p = layers + f * (3 * KBINS - 1);
        if (role == 0) {
            // W softmax -> cw, iw, boundaries
            float e[KBINS];
            float m = p[0];
            for (int i = 1; i < KBINS; ++i) m = fmaxf(m, p[i]);
            float s = 0.f;
            for (int i = 0; i < KBINS; ++i) { e[i] = expf(p[i] - m); s += e[i]; }
            float cs = 0.f;
            for (int k = 0; k < KBINS; ++k) {
                float Wk = (e[k] / s) * (2.f * BV);
                tbl[f * 40 + k * 8 + 0] = cs - BV;
                tbl[f * 40 + k * 8 + 1] = 1.f / Wk;
                cs += Wk;
                if (k < KBINS - 1) tbl[BND_OFF + f * 4 + k] = cs - BV;
            }
        } else if (role == 1) {
            // H softmax -> ch, h
            float e[KBINS];
            float m = p[KBINS];
            for (int i = 1; i < KBINS; ++i) m = fmaxf(m, p[KBINS + i]);
            float s = 0.f;
            for (int i = 0; i < KBINS; ++i) { e[i] = expf(p[KBINS + i] - m); s += e[i]; }
            float cs = 0.f;
            for (int k = 0; k < KBINS; ++k) {
                float Hk = (e[k] / s) * (2.f * BV);
                tbl[f * 40 + k * 8 + 2] = cs - BV;
                tbl[f * 40 + k * 8 + 3] = Hk;
                cs += Hk;
            }
        } else {
            // derivs -> dl, dr
            float dv[KBINS + 1];
            dv[0] = 1.f;
            dv[KBINS] = 1.f;
            for (int i = 0; i < KBINS - 1; ++i)
                dv[i + 1] = 2.f / (1.f + expf(-p[2 * KBINS + i]));
            for (int k = 0; k < KBINS; ++k) {
                tbl[f * 40 + k * 8 + 4] = dv[k];
                tbl[f * 40 + k * 8 + 5] = dv[k + 1];
            }
        }
    }
    if (t == 12) {
        tbl[176] = ip[0];
        tbl[177] = -0.5f * logf(2.f * (float)M_PI) - 0.5f * ip[1];
        tbl[178] = expf(-ip[1]);
    }
    __syncthreads();

    const float mu = tbl[176];
    const float c0 = tbl[177];
    const float ivar = tbl[178];
    // hoist per-flow boundaries into registers (iteration-invariant)
    f32x4 bbv[NF];
#pragma unroll
    for (int f = 0; f < NF; ++f)
        bbv[f] = *reinterpret_cast<const f32x4*>(&tbl[BND_OFF + f * 4]);

    const long n4 = n >> 2;
    const long tid = (long)blockIdx.x * blockDim.x + threadIdx.x;
    const long stride = (long)gridDim.x * blockDim.x;

    f32x4 cur;
    if (tid < n4) cur = reinterpret_cast<const f32x4*>(xin)[tid];

#pragma unroll 1
    for (long idx = tid; idx < n4; idx += stride) {
        // prefetch next quad (hides HBM latency under this quad's math)
        const long nidx = idx + stride;
        f32x4 nxt = cur;
        if (nidx < n4) nxt = reinterpret_cast<const f32x4*>(xin)[nidx];

        float x[4] = {cur.x, cur.y, cur.z, cur.w};
        float lda[4] = {0.f, 0.f, 0.f, 0.f};

#pragma unroll
        for (int f = 0; f < NF; ++f) {
            const f32x4 bb = bbv[f];
            float xc[4];
            f32x4 lo[4];
            f32x2 dd[4];
#pragma unroll
            for (int e = 0; e < 4; ++e) {
                xc[e] = fminf(fmaxf(x[e], -BV), BV);
                int k = (xc[e] >= bb.x) + (xc[e] >= bb.y) + (xc[e] >= bb.z) + (xc[e] >= bb.w);
                const float* tt = &tbl[f * 40 + k * 8];
                lo[e] = *reinterpret_cast<const f32x4*>(tt);
                dd[e] = *reinterpret_cast<const f32x2*>(tt + 4);
            }
#pragma unroll
            for (int e = 0; e < 4; ++e) {
                const bool inside = (x[e] == xc[e]);
                float cw = lo[e].x, iw = lo[e].y, ch = lo[e].z, h = lo[e].w;
                float dl = dd[e].x, dr = dd[e].y;
                float d = h * iw;
                float s2 = fmaf(-2.f, d, dl + dr);
                float th = (xc[e] - cw) * iw;
                float omt = 1.f - th;
                float tomt = th * omt;
                float th2 = th * th;
                float den = fmaf(s2, tomt, d);
                float rden = __builtin_amdgcn_rcpf(den);
                float zin = fmaf(h * fmaf(d, th2, dl * tomt), rden, ch);
                float dnum = (d * d) * fmaf(dr, th2, fmaf(d + d, tomt, dl * (omt * omt)));
                float ldin = __logf(dnum * (rden * rden));
                x[e] = inside ? zin : x[e];
                lda[e] += inside ? ldin : 0.f;
            }
        }

        f32x4 v0, v1, v2;
#pragma unroll
        for (int e = 0; e < 4; ++e) {
            float xm = x[e] - mu;
            v0[e] = fmaf(-0.5f * ivar, xm * xm, c0);
            v1[e] = lda[e];
            v2[e] = x[e];
        }
        __builtin_nontemporal_store(v0, reinterpret_cast<f32x4*>(out) + idx);
        __builtin_nontemporal_store(v1, reinterpret_cast<f32x4*>(out + n) + idx);
        __builtin_nontemporal_store(v2, reinterpret_cast<f32x4*>(out + 2 * n) + idx);
        cur = nxt;
    }

    // tail (n not divisible by 4)
    const long rem = n & 3;
    if (rem && tid < rem) {
        long i = n4 * 4 + tid;
        float x = xin[i];
        float lda = 0.f;
#pragma unroll
        for (int f = 0; f < NF; ++f) {
            float xc = fminf(fmaxf(x, -BV), BV);
            const bool inside = (x == xc);
            const float* bbp = &tbl[BND_OFF + f * 4];
            int k = (xc >= bbp[0]) + (xc >= bbp[1]) + (xc >= bbp[2]) + (xc >= bbp[3]);
            const float* tt = &tbl[f * 40 + k * 8];
            float cw = tt[0], iw = tt[1], ch = tt[2], h = tt[3];
            float dl = tt[4], dr = tt[5];
            float d = h * iw;
            float s2 = fmaf(-2.f, d, dl + dr);
            float th = (xc - cw) * iw;
            float omt = 1.f - th, tomt = th * omt, th2 = th * th;
            float den = fmaf(s2, tomt, d);
            float rden = __builtin_amdgcn_rcpf(den);
            float zin = fmaf(h * fmaf(d, th2, dl * tomt), rden, ch);
            float dnum = (d * d) * fmaf(dr, th2, fmaf(d + d, tomt, dl * (omt * omt)));
            float ldin = __logf(dnum * (rden * rden));
            x = inside ? zin : x;
            lda += inside ? ldin : 0.f;
        }
        float xm = x - mu;
        out[i] = fmaf(-0.5f * ivar, xm * xm, c0);
        out[n + i] = lda;
        out[2 * n + i] = x;
    }
}

extern "C" void kernel_launch(void* const* d_in, const int* in_sizes, int n_in,
                              void* d_out, int out_size, void* d_ws, size_t ws_size,
                              hipStream_t stream) {
    const float* x = (const float*)d_in[0];
    const float* layers = (const float*)d_in[1];
    const float* ip = (const float*)d_in[2];
    float* out = (float*)d_out;
    const long n = (long)in_sizes[0];

    const long n4 = (n + 3) >> 2;
    long blocks = (n4 + 255) / 256;
    if (blocks > 1024) blocks = 1024;
    if (blocks < 1) blocks = 1;
    hipLaunchKernelGGL(nsf_all, dim3((int)blocks), dim3(256), 0, stream, x, layers, ip, out, n);
}